// Round 1
// baseline (3271.891 us; speedup 1.0000x reference)
//
#include <hip/hip_runtime.h>
#include <math.h>

#define LATENT 256
#define HIDDEN 512
#define MAXN   64
#define BATCH  128
#define NPAIR  2016   // 64*63/2
#define G3     1536   // 3*HIDDEN

// ---------------------------------------------------------------------------
// ZC kernel: rows 0..127 -> Z[b,o] = z[b,:]@W_pre[o,:256]
//            rows 128..191 -> C[m,o] = pe[m,:]@W_pre[o,:256] + emb[m,:]@W_pre[o,256:512] + b_pre[o]
// ---------------------------------------------------------------------------
__global__ __launch_bounds__(256) void zc_kernel(
    const float* __restrict__ z, const float* __restrict__ pe,
    const float* __restrict__ emb, const float* __restrict__ W_pre,
    const float* __restrict__ b_pre, float* __restrict__ ZC)
{
  __shared__ float s1[256];
  __shared__ float s2[256];
  int row = blockIdx.x;     // 0..191
  int o = threadIdx.x;      // 0..255
  const float* wr = W_pre + (size_t)o * 512;
  if (row < 128) {
    s1[o] = z[row * 256 + o];
    __syncthreads();
    float acc = 0.f;
    #pragma unroll 8
    for (int k = 0; k < 256; k += 4) {
      float4 w4 = *(const float4*)(wr + k);
      float4 x4 = *(const float4*)(&s1[k]);
      acc += x4.x * w4.x; acc += x4.y * w4.y; acc += x4.z * w4.z; acc += x4.w * w4.w;
    }
    ZC[row * 256 + o] = acc;
  } else {
    int m = row - 128;
    s1[o] = pe[m * 256 + o];
    s2[o] = emb[m * 256 + o];
    __syncthreads();
    float acc = b_pre[o];
    #pragma unroll 8
    for (int k = 0; k < 256; k += 4) {
      float4 w4 = *(const float4*)(wr + k);
      float4 x4 = *(const float4*)(&s1[k]);
      acc += x4.x * w4.x; acc += x4.y * w4.y; acc += x4.z * w4.z; acc += x4.w * w4.w;
    }
    #pragma unroll 8
    for (int k = 0; k < 256; k += 4) {
      float4 w4 = *(const float4*)(wr + 256 + k);
      float4 x4 = *(const float4*)(&s2[k]);
      acc += x4.x * w4.x; acc += x4.y * w4.y; acc += x4.z * w4.z; acc += x4.w * w4.w;
    }
    ZC[row * 256 + o] = acc;
  }
}

// ---------------------------------------------------------------------------
// Generic f32 GEMM: C[M,N] = A[M,K] @ W[N,K]^T (+bias), optional per-row mask
// Tiles: 128x128x16, 256 threads, 8x8 micro-tile. N%128==0, K%16==0 required.
// MASK: row m -> b=m/64, t=m%64, zero if t >= n_nodes[b] (applied to A reads).
// ---------------------------------------------------------------------------
template<bool MASK>
__global__ __launch_bounds__(256) void gemm_kernel(
    const float* __restrict__ A, int lda,
    const float* __restrict__ W, int ldw,
    const float* __restrict__ bias,
    float* __restrict__ C, int ldc,
    int M, int N, int K,
    const int* __restrict__ n_nodes)
{
  __shared__ float As[16][136];
  __shared__ float Ws[16][136];
  const int tid = threadIdx.x;
  const int tx = tid & 15, ty = tid >> 4;
  const int row0 = blockIdx.y * 128, col0 = blockIdx.x * 128;

  float acc[8][8];
  #pragma unroll
  for (int i = 0; i < 8; i++)
    #pragma unroll
    for (int j = 0; j < 8; j++) acc[i][j] = 0.f;

  for (int k0 = 0; k0 < K; k0 += 16) {
    #pragma unroll
    for (int s = 0; s < 2; s++) {
      int q = tid + 256 * s;
      int r = q >> 2;
      int c4 = (q & 3) << 2;
      int gm = row0 + r;
      float4 v = make_float4(0.f, 0.f, 0.f, 0.f);
      if (gm < M) {
        v = *(const float4*)(A + (size_t)gm * lda + k0 + c4);
        if (MASK) {
          int bb = gm >> 6, tt = gm & 63;
          if (tt >= n_nodes[bb]) v = make_float4(0.f, 0.f, 0.f, 0.f);
        }
      }
      As[c4 + 0][r] = v.x; As[c4 + 1][r] = v.y; As[c4 + 2][r] = v.z; As[c4 + 3][r] = v.w;
      int gn = col0 + r;
      float4 w = *(const float4*)(W + (size_t)gn * ldw + k0 + c4);
      Ws[c4 + 0][r] = w.x; Ws[c4 + 1][r] = w.y; Ws[c4 + 2][r] = w.z; Ws[c4 + 3][r] = w.w;
    }
    __syncthreads();
    #pragma unroll
    for (int kk = 0; kk < 16; kk++) {
      float4 a0 = *(const float4*)&As[kk][ty * 8];
      float4 a1 = *(const float4*)&As[kk][ty * 8 + 4];
      float4 b0 = *(const float4*)&Ws[kk][tx * 8];
      float4 b1 = *(const float4*)&Ws[kk][tx * 8 + 4];
      float av[8] = {a0.x, a0.y, a0.z, a0.w, a1.x, a1.y, a1.z, a1.w};
      float bv[8] = {b0.x, b0.y, b0.z, b0.w, b1.x, b1.y, b1.z, b1.w};
      #pragma unroll
      for (int i = 0; i < 8; i++)
        #pragma unroll
        for (int j = 0; j < 8; j++)
          acc[i][j] += av[i] * bv[j];
    }
    __syncthreads();
  }

  float bb[8];
  #pragma unroll
  for (int j = 0; j < 8; j++) bb[j] = bias ? bias[col0 + tx * 8 + j] : 0.f;
  #pragma unroll
  for (int i = 0; i < 8; i++) {
    int gm = row0 + ty * 8 + i;
    if (gm < M) {
      float* out = C + (size_t)gm * ldc + col0 + tx * 8;
      float4 o0 = make_float4(acc[i][0] + bb[0], acc[i][1] + bb[1], acc[i][2] + bb[2], acc[i][3] + bb[3]);
      float4 o1 = make_float4(acc[i][4] + bb[4], acc[i][5] + bb[5], acc[i][6] + bb[6], acc[i][7] + bb[7]);
      *(float4*)out = o0;
      *(float4*)(out + 4) = o1;
    }
  }
}

// ---------------------------------------------------------------------------
// WAB precompute: WAB[o,k] (1024x512)
//   o<512 : sum_j adj_W1[o, j]     * node_W[j, k]
//   o>=512: sum_j adj_W1[o-512, 512+j] * node_W[j, k]
// ---------------------------------------------------------------------------
__global__ __launch_bounds__(256) void wab_kernel(
    const float* __restrict__ adj_W1, const float* __restrict__ node_W,
    float* __restrict__ WAB)
{
  int k = blockIdx.x * 256 + threadIdx.x;  // 0..511
  int o0 = blockIdx.y * 8;
  int sel = blockIdx.z;
  const float* a1 = adj_W1 + (sel ? 512 : 0);
  float acc[8] = {0.f, 0.f, 0.f, 0.f, 0.f, 0.f, 0.f, 0.f};
  for (int j = 0; j < 512; j++) {
    float w = node_W[(size_t)j * 512 + k];
    #pragma unroll
    for (int oo = 0; oo < 8; oo++)
      acc[oo] += a1[(size_t)(o0 + oo) * 1024 + j] * w;
  }
  #pragma unroll
  for (int oo = 0; oo < 8; oo++)
    WAB[(size_t)(sel * 512 + o0 + oo) * 512 + k] = acc[oo];
}

// ---------------------------------------------------------------------------
// GRU step: one timestep, fused gh GEMM (3 gate dots / thread) + cell.
// Block: 256 thr = 16 b x 16 o. Grid (512/16, 128/16). Register-prefetch
// pipelined LDS staging of Whh rows (48 x 128 chunk) and h_prev (16 x 128).
// MODE 0: gi = mask*(ZCW[b] + ZCW[128+t]) + bih0    (layer 0)
// MODE 1: gi = GI1[(b*64+t)]                        (layer 1, bias pre-added)
// ---------------------------------------------------------------------------
template<int MODE>
__global__ __launch_bounds__(256) void gru_step_kernel(
    const float* __restrict__ Whh, const float* __restrict__ bhh,
    float* __restrict__ Hbuf,
    const float* __restrict__ gi, const float* __restrict__ bih,
    const int* __restrict__ n_nodes, int t)
{
  __shared__ float h_s[16][132];
  __shared__ float w_s[48][132];
  const int tid = threadIdx.x;
  const int ol = tid & 15, bl = tid >> 4;
  const int o0 = blockIdx.x * 16, b0 = blockIdx.y * 16;
  const int o = o0 + ol, b = b0 + bl;

  float accr = 0.f, accz = 0.f, accn = 0.f;

  if (t > 0) {
    float4 wreg[6], hreg[2];
    auto load_chunk = [&](int k0) {
      #pragma unroll
      for (int s = 0; s < 6; s++) {
        int q = tid + 256 * s;
        int r = q >> 5, c4 = (q & 31) << 2;
        int grow = (r >> 4) * 512 + o0 + (r & 15);
        wreg[s] = *(const float4*)(Whh + (size_t)grow * 512 + k0 + c4);
      }
      #pragma unroll
      for (int s = 0; s < 2; s++) {
        int q = tid + 256 * s;
        int r = q >> 5, c4 = (q & 31) << 2;
        hreg[s] = *(const float4*)(Hbuf + ((size_t)((b0 + r) * 64 + (t - 1))) * 512 + k0 + c4);
      }
    };
    load_chunk(0);
    for (int c = 0; c < 4; c++) {
      __syncthreads();
      #pragma unroll
      for (int s = 0; s < 6; s++) {
        int q = tid + 256 * s; int r = q >> 5, c4 = (q & 31) << 2;
        *(float4*)&w_s[r][c4] = wreg[s];
      }
      #pragma unroll
      for (int s = 0; s < 2; s++) {
        int q = tid + 256 * s; int r = q >> 5, c4 = (q & 31) << 2;
        *(float4*)&h_s[r][c4] = hreg[s];
      }
      __syncthreads();
      if (c < 3) load_chunk((c + 1) * 128);
      #pragma unroll 8
      for (int kk = 0; kk < 128; kk += 4) {
        float4 h4 = *(const float4*)&h_s[bl][kk];
        float4 wr = *(const float4*)&w_s[ol][kk];
        float4 wz = *(const float4*)&w_s[16 + ol][kk];
        float4 wn = *(const float4*)&w_s[32 + ol][kk];
        accr += h4.x * wr.x; accr += h4.y * wr.y; accr += h4.z * wr.z; accr += h4.w * wr.w;
        accz += h4.x * wz.x; accz += h4.y * wz.y; accz += h4.z * wz.z; accz += h4.w * wz.w;
        accn += h4.x * wn.x; accn += h4.y * wn.y; accn += h4.z * wn.z; accn += h4.w * wn.w;
      }
    }
  }

  float hr = accr + bhh[o];
  float hz = accz + bhh[HIDDEN + o];
  float hn = accn + bhh[2 * HIDDEN + o];
  float ir, iz, inn;
  if (MODE == 0) {
    bool mk = (t < n_nodes[b]);
    float vr = gi[(size_t)b * G3 + o]              + gi[(size_t)(128 + t) * G3 + o];
    float vz = gi[(size_t)b * G3 + HIDDEN + o]     + gi[(size_t)(128 + t) * G3 + HIDDEN + o];
    float vn = gi[(size_t)b * G3 + 2 * HIDDEN + o] + gi[(size_t)(128 + t) * G3 + 2 * HIDDEN + o];
    ir  = (mk ? vr : 0.f) + bih[o];
    iz  = (mk ? vz : 0.f) + bih[HIDDEN + o];
    inn = (mk ? vn : 0.f) + bih[2 * HIDDEN + o];
  } else {
    const float* g = gi + ((size_t)(b * 64 + t)) * G3;
    ir = g[o]; iz = g[HIDDEN + o]; inn = g[2 * HIDDEN + o];
  }
  float rg = 1.f / (1.f + expf(-(ir + hr)));
  float zg = 1.f / (1.f + expf(-(iz + hz)));
  float ng = tanhf(inn + rg * hn);
  float hp = (t > 0) ? Hbuf[((size_t)(b * 64 + t - 1)) * 512 + o] : 0.f;
  float hnew = (1.f - zg) * ng + zg * hp;
  Hbuf[((size_t)(b * 64 + t)) * 512 + o] = hnew;
}

// ---------------------------------------------------------------------------
// Diagonal zero (pairs cover all off-diagonal entries of the output)
// ---------------------------------------------------------------------------
__global__ void diag_kernel(float* __restrict__ adj)
{
  int x = blockIdx.x * 256 + threadIdx.x;
  if (x < 8192) {
    int b = x >> 6, d = x & 63;
    adj[(size_t)b * 4096 + d * 65] = 0.f;
  }
}

// ---------------------------------------------------------------------------
// Pair kernel: one wave per (b, pair). hmid = relu(A_i + B_j + b1),
// logits = hmid @ W2^T + b2, gumbel hard argmax, symmetric scatter.
// ---------------------------------------------------------------------------
__global__ __launch_bounds__(256) void pair_kernel(
    const float* __restrict__ AB, const float* __restrict__ b1,
    const float* __restrict__ W2, const float* __restrict__ b2,
    const float* __restrict__ gu, const int* __restrict__ n_nodes,
    float* __restrict__ adj)
{
  int wid = blockIdx.x * 4 + (threadIdx.x >> 6);
  int lane = threadIdx.x & 63;
  int b = wid / NPAIR;
  int p = wid - b * NPAIR;

  // invert triu(64, k=1) linear index: S(i) = i*(127-i)/2
  float fp = (float)p;
  int i = (int)((127.0f - sqrtf(16129.0f - 8.0f * fp)) * 0.5f);
  if (i < 0) i = 0;
  if (i > 62) i = 62;
  while (i < 62 && (i + 1) * (126 - i) / 2 <= p) i++;
  while (i > 0 && i * (127 - i) / 2 > p) i--;
  int j = p - i * (127 - i) / 2 + i + 1;

  const float* arow = AB + ((size_t)(b * 64 + i)) * 1024;
  const float* brow = AB + ((size_t)(b * 64 + j)) * 1024 + 512;
  int k0 = lane * 8;

  float4 a0 = *(const float4*)(arow + k0);
  float4 a1 = *(const float4*)(arow + k0 + 4);
  float4 q0 = *(const float4*)(brow + k0);
  float4 q1 = *(const float4*)(brow + k0 + 4);
  float4 c0 = *(const float4*)(b1 + k0);
  float4 c1 = *(const float4*)(b1 + k0 + 4);

  float h0 = fmaxf(a0.x + q0.x + c0.x, 0.f);
  float h1 = fmaxf(a0.y + q0.y + c0.y, 0.f);
  float h2 = fmaxf(a0.z + q0.z + c0.z, 0.f);
  float h3 = fmaxf(a0.w + q0.w + c0.w, 0.f);
  float h4 = fmaxf(a1.x + q1.x + c1.x, 0.f);
  float h5 = fmaxf(a1.y + q1.y + c1.y, 0.f);
  float h6 = fmaxf(a1.z + q1.z + c1.z, 0.f);
  float h7 = fmaxf(a1.w + q1.w + c1.w, 0.f);

  float4 w00 = *(const float4*)(W2 + k0);
  float4 w01 = *(const float4*)(W2 + k0 + 4);
  float4 w10 = *(const float4*)(W2 + 512 + k0);
  float4 w11 = *(const float4*)(W2 + 512 + k0 + 4);

  float acc0 = h0 * w00.x + h1 * w00.y + h2 * w00.z + h3 * w00.w
             + h4 * w01.x + h5 * w01.y + h6 * w01.z + h7 * w01.w;
  float acc1 = h0 * w10.x + h1 * w10.y + h2 * w10.z + h3 * w10.w
             + h4 * w11.x + h5 * w11.y + h6 * w11.z + h7 * w11.w;

  #pragma unroll
  for (int off = 32; off > 0; off >>= 1) {
    acc0 += __shfl_xor(acc0, off, 64);
    acc1 += __shfl_xor(acc1, off, 64);
  }

  if (lane == 0) {
    float s0 = acc0 + b2[0];
    float s1 = acc1 + b2[1];
    const float* u = gu + ((size_t)(b * NPAIR + p)) * 2;
    float g0 = -logf(-logf(u[0] + 1e-10f) + 1e-10f);
    float g1 = -logf(-logf(u[1] + 1e-10f) + 1e-10f);
    int n = n_nodes[b];
    float val = 0.f;
    if (i < n && j < n) val = ((s0 + g0) >= (s1 + g1)) ? 1.f : 0.f;
    adj[(size_t)b * 4096 + i * 64 + j] = val;
    adj[(size_t)b * 4096 + j * 64 + i] = val;
  }
}

// ---------------------------------------------------------------------------
extern "C" void kernel_launch(void* const* d_in, const int* in_sizes, int n_in,
                              void* d_out, int out_size, void* d_ws, size_t ws_size,
                              hipStream_t stream)
{
  (void)in_sizes; (void)n_in; (void)out_size; (void)ws_size;

  const float* z       = (const float*)d_in[0];
  const int*   n_nodes = (const int*)d_in[1];
  // d_in[2] = n_edges (unused by reference)
  const float* gu      = (const float*)d_in[3];
  const float* emb     = (const float*)d_in[4];
  const float* pe      = (const float*)d_in[5];
  const float* W_pre   = (const float*)d_in[6];
  const float* b_pre   = (const float*)d_in[7];
  const float* Wih0    = (const float*)d_in[8];
  const float* Whh0    = (const float*)d_in[9];
  const float* bih0    = (const float*)d_in[10];
  const float* bhh0    = (const float*)d_in[11];
  const float* Wih1    = (const float*)d_in[12];
  const float* Whh1    = (const float*)d_in[13];
  const float* bih1    = (const float*)d_in[14];
  const float* bhh1    = (const float*)d_in[15];
  const float* node_W  = (const float*)d_in[16];
  const float* adj_W1  = (const float*)d_in[17];
  const float* adj_b1  = (const float*)d_in[18];
  const float* adj_W2  = (const float*)d_in[19];
  const float* adj_b2  = (const float*)d_in[20];
  float* adj = (float*)d_out;

  // workspace layout (bytes)
  char* ws = (char*)d_ws;
  float* ZC  = (float*)(ws + 0);         // 192 x 256        (196608 B)
  float* ZCW = (float*)(ws + 196608);    // 192 x 1536       (1179648 B)
  float* WAB = (float*)(ws + 1376256);   // 1024 x 512       (2097152 B)
  float* H1  = (float*)(ws + 3473408);   // 8192 x 512       (16 MiB)
  float* H2  = (float*)(ws + 20250624);  // 8192 x 512       (16 MiB)
  float* GI1 = (float*)(ws + 37027840);  // 8192 x 1536      (48 MiB)
  float* AB  = GI1;                      // 8192 x 1024 aliases GI1 (dead by then)

  // 1) tiny projections Z (per-batch) and C (per-position incl. bias)
  zc_kernel<<<192, 256, 0, stream>>>(z, pe, emb, W_pre, b_pre, ZC);

  // 2) ZCW = ZC @ Wih0^T   (192 x 1536, K=256)
  gemm_kernel<false><<<dim3(12, 2), 256, 0, stream>>>(
      ZC, 256, Wih0, 256, nullptr, ZCW, 1536, 192, 1536, 256, nullptr);

  // 3) WAB[o,k]: folded (adj_W1a @ node_W), (adj_W1b @ node_W)
  wab_kernel<<<dim3(2, 64, 2), 256, 0, stream>>>(adj_W1, node_W, WAB);

  // 4) GRU layer 0 recurrence
  for (int t = 0; t < 64; t++)
    gru_step_kernel<0><<<dim3(32, 8), 256, 0, stream>>>(
        Whh0, bhh0, H1, ZCW, bih0, n_nodes, t);

  // 5) GI1 = H1 @ Wih1^T + bih1   (8192 x 1536, K=512)
  gemm_kernel<false><<<dim3(12, 64), 256, 0, stream>>>(
      H1, 512, Wih1, 512, bih1, GI1, 1536, 8192, 1536, 512, nullptr);

  // 6) GRU layer 1 recurrence
  for (int t = 0; t < 64; t++)
    gru_step_kernel<1><<<dim3(32, 8), 256, 0, stream>>>(
        Whh1, bhh1, H2, GI1, nullptr, nullptr, t);

  // 7) AB = (mask * H2) @ WAB^T   (8192 x 1024, K=512)
  gemm_kernel<true><<<dim3(8, 64), 256, 0, stream>>>(
      H2, 512, WAB, 512, nullptr, AB, 1024, 8192, 1024, 512, n_nodes);

  // 8) output: zero diagonal, then all pairs (both symmetric halves)
  diag_kernel<<<32, 256, 0, stream>>>(adj);
  pair_kernel<<<64512, 256, 0, stream>>>(AB, adj_b1, adj_W2, adj_b2, gu, n_nodes, adj);
}